// Round 1
// baseline (733.689 us; speedup 1.0000x reference)
//
#include <hip/hip_runtime.h>
#include <math.h>

typedef short short8 __attribute__((ext_vector_type(8)));
typedef short short4v __attribute__((ext_vector_type(4)));
typedef float float4v __attribute__((ext_vector_type(4)));

// bf16 round-to-nearest-even from fp32, as raw bits in a short
__device__ __forceinline__ short f2bf(float f) {
    union { float f; unsigned u; } v; v.f = f;
    unsigned r = (v.u + 0x7FFFu + ((v.u >> 16) & 1u)) >> 16;
    return (short)r;
}

// ---------------- fp32 -> bf16 convert (vectorized) ----------------
__global__ void cvt_kernel(const float* __restrict__ src, short* __restrict__ dst, int n4) {
    int i = blockIdx.x * blockDim.x + threadIdx.x;
    if (i < n4) {
        float4v v = ((const float4v*)src)[i];
        short4v o;
        o[0] = f2bf(v[0]); o[1] = f2bf(v[1]); o[2] = f2bf(v[2]); o[3] = f2bf(v[3]);
        ((short4v*)dst)[i] = o;
    }
}

// ---------------- sign-based row masks: sign(sum |x|) ----------------
// rows 0..16383 -> queries/qmask, 16384..32767 -> keys/kmask
__global__ void mask_kernel(const float* __restrict__ q, const float* __restrict__ k,
                            float* __restrict__ qm, float* __restrict__ km) {
    int row = blockIdx.x;
    int lane = threadIdx.x;
    const float* src = (row < 16384) ? q : k;
    float* dst = (row < 16384) ? qm : km;
    int r = row & 16383;
    const float4v* p = (const float4v*)(src + (size_t)r * 512);
    float4v a = p[lane];
    float4v b = p[lane + 64];
    float s = fabsf(a[0]) + fabsf(a[1]) + fabsf(a[2]) + fabsf(a[3])
            + fabsf(b[0]) + fabsf(b[1]) + fabsf(b[2]) + fabsf(b[3]);
    #pragma unroll
    for (int off = 1; off < 64; off <<= 1) s += __shfl_xor(s, off, 64);
    if (lane == 0) dst[r] = (s > 0.f) ? 1.f : 0.f;
}

// ---------------- projection GEMM: out[m][n] = sum_k X[m][k]*W[n][k] + b[n] ----------------
// X: [16384,512] bf16, W: [512,512] bf16 (row n contiguous in k), out bf16
__global__ __launch_bounds__(256) void proj_kernel(const short* __restrict__ X,
                                                   const short* __restrict__ W,
                                                   const float* __restrict__ bias,
                                                   short* __restrict__ out) {
    int tid = threadIdx.x;
    int lane = tid & 63, wv = tid >> 6;
    int col = lane & 15, quad = lane >> 4;
    int m0 = blockIdx.x * 64 + wv * 16;
    int n0 = blockIdx.y * 64;
    float4v acc[4];
    #pragma unroll
    for (int nt = 0; nt < 4; ++nt) { acc[nt][0]=0.f; acc[nt][1]=0.f; acc[nt][2]=0.f; acc[nt][3]=0.f; }
    const short* xrow = X + (size_t)(m0 + col) * 512 + quad * 8;
    const short* wrow = W + (size_t)(n0 + col) * 512 + quad * 8;
    #pragma unroll
    for (int kc = 0; kc < 16; ++kc) {
        short8 a = *(const short8*)(xrow + kc * 32);
        #pragma unroll
        for (int nt = 0; nt < 4; ++nt) {
            short8 bf = *(const short8*)(wrow + (size_t)nt * 16 * 512 + kc * 32);
            acc[nt] = __builtin_amdgcn_mfma_f32_16x16x32_bf16(a, bf, acc[nt], 0, 0, 0);
        }
    }
    #pragma unroll
    for (int nt = 0; nt < 4; ++nt) {
        float bv = bias[n0 + nt * 16 + col];
        #pragma unroll
        for (int r = 0; r < 4; ++r) {
            int row = m0 + quad * 4 + r;
            out[(size_t)row * 512 + n0 + nt * 16 + col] = f2bf(acc[nt][r] + bv);
        }
    }
}

// ---------------- fused attention ----------------
// grid: (qtile=8, h=8, b=32), block 256 (4 waves, 16 q-rows per wave)
__global__ __launch_bounds__(256) void attn_kernel(
    const short* __restrict__ Q, const short* __restrict__ K, const short* __restrict__ V,
    const float* __restrict__ qmask, const float* __restrict__ kmask,
    const int* __restrict__ caus, float* __restrict__ out, float* __restrict__ aw) {
    __shared__ short vt[64 * 72];        // V^T chunk: vt[d][kk], stride 72 (2-way bank alias = free)
    __shared__ short wl[4 * 16 * 72];    // per-wave w chunk (bf16, A-layout source)

    int tid = threadIdx.x;
    int lane = tid & 63, wv = tid >> 6;
    int col = lane & 15, quad = lane >> 4;
    int qt = blockIdx.x, h = blockIdx.y, b = blockIdx.z;
    int q0 = qt * 64 + wv * 16;          // this wave's q base (global within L)
    size_t rowbase = (size_t)b * 512;
    bool causal = (*caus) != 0;

    // Q A-frags (lane m=col holds k=quad*8+j, two 32-k chunks cover dh=64)
    short8 aQ0, aQ1;
    {
        const short* qp = Q + (rowbase + q0 + col) * 512 + h * 64 + quad * 8;
        aQ0 = *(const short8*)(qp);
        aQ1 = *(const short8*)(qp + 32);
    }

    // scores: 32 tiles of 16x16; lane holds rows quad*4+r, col = t*16 + (lane&15)
    float4v sc[32];
    const short* kp = K + (rowbase + col) * 512 + h * 64 + quad * 8;
    const float* kmp = kmask + b * 512;
    #pragma unroll
    for (int t = 0; t < 32; ++t) {
        short8 b0 = *(const short8*)(kp + (size_t)(t * 16) * 512);
        short8 b1 = *(const short8*)(kp + (size_t)(t * 16) * 512 + 32);
        float4v s; s[0]=0.f; s[1]=0.f; s[2]=0.f; s[3]=0.f;
        s = __builtin_amdgcn_mfma_f32_16x16x32_bf16(aQ0, b0, s, 0, 0, 0);
        s = __builtin_amdgcn_mfma_f32_16x16x32_bf16(aQ1, b1, s, 0, 0, 0);
        int kcol = t * 16 + col;
        float km = kmp[kcol];
        #pragma unroll
        for (int r = 0; r < 4; ++r) {
            float v = s[r] * 0.125f;  // 1/sqrt(64)
            int qg = q0 + quad * 4 + r;
            bool masked = (km == 0.f) || (causal && (kcol > qg));
            sc[t][r] = masked ? -INFINITY : v;
        }
    }

    // softmax over k (512 values per q-row: 32 per lane x 16 lanes in the quad-group)
    float mx[4], sm[4], inv[4];
    #pragma unroll
    for (int r = 0; r < 4; ++r) mx[r] = -INFINITY;
    #pragma unroll
    for (int t = 0; t < 32; ++t)
        #pragma unroll
        for (int r = 0; r < 4; ++r) mx[r] = fmaxf(mx[r], sc[t][r]);
    #pragma unroll
    for (int r = 0; r < 4; ++r) {
        #pragma unroll
        for (int off = 1; off < 16; off <<= 1) mx[r] = fmaxf(mx[r], __shfl_xor(mx[r], off, 64));
    }
    #pragma unroll
    for (int r = 0; r < 4; ++r) sm[r] = 0.f;
    #pragma unroll
    for (int t = 0; t < 32; ++t)
        #pragma unroll
        for (int r = 0; r < 4; ++r) {
            float s = sc[t][r];
            float e = (s == -INFINITY) ? 0.f : __expf(s - mx[r]);
            sc[t][r] = e;
            sm[r] += e;
        }
    #pragma unroll
    for (int r = 0; r < 4; ++r) {
        #pragma unroll
        for (int off = 1; off < 16; off <<= 1) sm[r] += __shfl_xor(sm[r], off, 64);
    }
    const float* qmp = qmask + b * 512;
    #pragma unroll
    for (int r = 0; r < 4; ++r) {
        float qm = qmp[q0 + quad * 4 + r];
        inv[r] = (sm[r] > 0.f) ? (qm / sm[r]) : 0.f;  // nan_to_num + post-softmax query mask
    }
    #pragma unroll
    for (int t = 0; t < 32; ++t)
        #pragma unroll
        for (int r = 0; r < 4; ++r) sc[t][r] *= inv[r];

    // write attention weights [B][H][Lq][Lk]
    float* awp = aw + ((size_t)b * 8 + h) * 512 * 512;
    #pragma unroll
    for (int t = 0; t < 32; ++t) {
        int kcol = t * 16 + col;
        #pragma unroll
        for (int r = 0; r < 4; ++r) {
            int qg = q0 + quad * 4 + r;
            awp[(size_t)qg * 512 + kcol] = sc[t][r];
        }
    }

    // PV: O[q][d] = sum_k w[q][k] * V[k][d], chunked over k in 8 chunks of 64
    float4v O[4];
    #pragma unroll
    for (int nt = 0; nt < 4; ++nt) { O[nt][0]=0.f; O[nt][1]=0.f; O[nt][2]=0.f; O[nt][3]=0.f; }
    short* wlw = wl + wv * (16 * 72);
    #pragma unroll
    for (int c = 0; c < 8; ++c) {
        __syncthreads();
        // stage V^T chunk: vt[d][kk] <- V[b*512 + c*64 + kk][h*64 + d]
        #pragma unroll
        for (int i = 0; i < 16; ++i) {
            int idx = i * 256 + tid;
            int kk = idx >> 6, d = idx & 63;
            vt[d * 72 + kk] = V[(rowbase + c * 64 + kk) * 512 + h * 64 + d];
        }
        // stage this wave's w chunk as bf16 in [q][kk] layout
        #pragma unroll
        for (int tl = 0; tl < 4; ++tl) {
            #pragma unroll
            for (int r = 0; r < 4; ++r)
                wlw[(quad * 4 + r) * 72 + tl * 16 + col] = f2bf(sc[c * 4 + tl][r]);
        }
        __syncthreads();
        #pragma unroll
        for (int sub = 0; sub < 2; ++sub) {
            short8 aW = *(const short8*)(wlw + col * 72 + sub * 32 + quad * 8);
            #pragma unroll
            for (int nt = 0; nt < 4; ++nt) {
                short8 bV = *(const short8*)(vt + (nt * 16 + col) * 72 + sub * 32 + quad * 8);
                O[nt] = __builtin_amdgcn_mfma_f32_16x16x32_bf16(aW, bV, O[nt], 0, 0, 0);
            }
        }
    }
    // out[b][l][h*64+d]
    #pragma unroll
    for (int nt = 0; nt < 4; ++nt) {
        #pragma unroll
        for (int r = 0; r < 4; ++r) {
            int qg = q0 + quad * 4 + r;
            out[(rowbase + qg) * 512 + h * 64 + nt * 16 + col] = O[nt][r];
        }
    }
}

extern "C" void kernel_launch(void* const* d_in, const int* in_sizes, int n_in,
                              void* d_out, int out_size, void* d_ws, size_t ws_size,
                              hipStream_t stream) {
    const float* queries = (const float*)d_in[0];
    const float* keys    = (const float*)d_in[1];
    const float* Wq      = (const float*)d_in[2];
    const float* bq      = (const float*)d_in[3];
    const float* Wk      = (const float*)d_in[4];
    const float* bk      = (const float*)d_in[5];
    const float* Wv      = (const float*)d_in[6];
    const float* bv      = (const float*)d_in[7];
    const int*   caus    = (const int*)d_in[8];

    const size_t NE = (size_t)16384 * 512;  // 8,388,608 elements per [B*L, D] tensor
    short* qbf = (short*)d_ws;
    short* kbf = qbf + NE;
    short* Qb  = kbf + NE;
    short* Kb  = Qb + NE;
    short* Vb  = Kb + NE;
    short* wqb = Vb + NE;
    short* wkb = wqb + 512 * 512;
    short* wvb = wkb + 512 * 512;
    float* qm  = (float*)(wvb + 512 * 512);
    float* km  = qm + 32 * 512;

    // fp32 -> bf16 converts
    cvt_kernel<<<8192, 256, 0, stream>>>(queries, qbf, 2097152);
    cvt_kernel<<<8192, 256, 0, stream>>>(keys,    kbf, 2097152);
    cvt_kernel<<<256,  256, 0, stream>>>(Wq, wqb, 65536);
    cvt_kernel<<<256,  256, 0, stream>>>(Wk, wkb, 65536);
    cvt_kernel<<<256,  256, 0, stream>>>(Wv, wvb, 65536);
    // sign masks
    mask_kernel<<<32768, 64, 0, stream>>>(queries, keys, qm, km);
    // projections
    dim3 pg(256, 8);
    proj_kernel<<<pg, 256, 0, stream>>>(qbf, wqb, bq, Qb);
    proj_kernel<<<pg, 256, 0, stream>>>(kbf, wkb, bk, Kb);
    proj_kernel<<<pg, 256, 0, stream>>>(kbf, wvb, bv, Vb);
    // fused attention
    float* outp = (float*)d_out;
    float* awp  = outp + 8388608;
    dim3 ag(8, 8, 32);
    attn_kernel<<<ag, 256, 0, stream>>>(Qb, Kb, Vb, qm, km, caus, outp, awp);
}

// Round 2
// 540.214 us; speedup vs baseline: 1.3581x; 1.3581x over previous
//
#include <hip/hip_runtime.h>
#include <math.h>

typedef short short8 __attribute__((ext_vector_type(8)));
typedef short short4v __attribute__((ext_vector_type(4)));
typedef float float4v __attribute__((ext_vector_type(4)));

// bf16 round-to-nearest-even from fp32, as raw bits in a short
__device__ __forceinline__ short f2bf(float f) {
    union { float f; unsigned u; } v; v.f = f;
    unsigned r = (v.u + 0x7FFFu + ((v.u >> 16) & 1u)) >> 16;
    return (short)r;
}

__device__ __forceinline__ void async16(const short* g, short* l) {
    __builtin_amdgcn_global_load_lds(
        (const __attribute__((address_space(1))) unsigned*)g,
        (__attribute__((address_space(3))) unsigned*)l, 16, 0, 0);
}

// ---------------- fp32 -> bf16 convert (weights) ----------------
__global__ void cvt_kernel(const float* __restrict__ src, short* __restrict__ dst, int n4) {
    int i = blockIdx.x * blockDim.x + threadIdx.x;
    if (i < n4) {
        float4v v = ((const float4v*)src)[i];
        short4v o;
        o[0] = f2bf(v[0]); o[1] = f2bf(v[1]); o[2] = f2bf(v[2]); o[3] = f2bf(v[3]);
        ((short4v*)dst)[i] = o;
    }
}

// ---------------- fused fp32->bf16 + sign-mask for queries/keys ----------------
// 4 rows per block (1 row per wave); rows 0..16383 queries, 16384..32767 keys
__global__ __launch_bounds__(256) void cvtmask_kernel(
    const float* __restrict__ q, const float* __restrict__ k,
    short* __restrict__ qb, short* __restrict__ kb,
    float* __restrict__ qm, float* __restrict__ km) {
    int tid = threadIdx.x;
    int lane = tid & 63, wv = tid >> 6;
    int row = blockIdx.x * 4 + wv;
    const float* src; short* dst; float* msk; int r;
    if (row < 16384) { src = q; dst = qb; msk = qm; r = row; }
    else             { src = k; dst = kb; msk = km; r = row - 16384; }
    const float4v* p = (const float4v*)(src + (size_t)r * 512);
    float4v a = p[lane];
    float4v b = p[lane + 64];
    short4v o1, o2;
    o1[0] = f2bf(a[0]); o1[1] = f2bf(a[1]); o1[2] = f2bf(a[2]); o1[3] = f2bf(a[3]);
    o2[0] = f2bf(b[0]); o2[1] = f2bf(b[1]); o2[2] = f2bf(b[2]); o2[3] = f2bf(b[3]);
    short4v* d4 = (short4v*)(dst + (size_t)r * 512);
    d4[lane] = o1;
    d4[lane + 64] = o2;
    float s = fabsf(a[0]) + fabsf(a[1]) + fabsf(a[2]) + fabsf(a[3])
            + fabsf(b[0]) + fabsf(b[1]) + fabsf(b[2]) + fabsf(b[3]);
    #pragma unroll
    for (int off = 1; off < 64; off <<= 1) s += __shfl_xor(s, off, 64);
    if (lane == 0) msk[r] = (s > 0.f) ? 1.f : 0.f;
}

// ---------------- fused projection GEMM (m97 structure) ----------------
// out[m][n] = sum_k X[m][k]*W[n][k] + bias[n];  z=0: Q=queries@Wq, z=1: K=keys@Wk, z=2: V=keys@Wv
// 128x128 tile, BK=32, global_load_lds staging, 4 waves x (64x64)
__global__ __launch_bounds__(256) void proj_kernel(
    const short* __restrict__ Xq, const short* __restrict__ Xk,
    const short* __restrict__ Wqp, const short* __restrict__ Wkp, const short* __restrict__ Wvp,
    const float* __restrict__ bqp, const float* __restrict__ bkp, const float* __restrict__ bvp,
    short* __restrict__ Qo, short* __restrict__ Ko, short* __restrict__ Vo) {
    __shared__ short As[128 * 32];
    __shared__ short Bs[128 * 32];
    int z = blockIdx.z;
    const short* X    = (z == 0) ? Xq  : Xk;
    const short* W    = (z == 0) ? Wqp : (z == 1) ? Wkp : Wvp;
    const float* bias = (z == 0) ? bqp : (z == 1) ? bkp : bvp;
    short* out        = (z == 0) ? Qo  : (z == 1) ? Ko  : Vo;

    int tid = threadIdx.x;
    int lane = tid & 63, wv = tid >> 6;
    int col = lane & 15, quad = lane >> 4;
    int m0 = blockIdx.x * 128;
    int n0 = blockIdx.y * 128;
    int msub = (wv & 1) * 64, nsub = (wv >> 1) * 64;

    float4v acc[4][4];
    #pragma unroll
    for (int mt = 0; mt < 4; ++mt)
        #pragma unroll
        for (int nt = 0; nt < 4; ++nt) { acc[mt][nt][0]=0.f; acc[mt][nt][1]=0.f; acc[mt][nt][2]=0.f; acc[mt][nt][3]=0.f; }

    int rowS = tid >> 2;   // 0..63
    int seg  = tid & 3;    // 16B segment within a 64B row
    const short* gA0 = X + (size_t)(m0 + rowS) * 512 + seg * 8;
    const short* gA1 = X + (size_t)(m0 + 64 + rowS) * 512 + seg * 8;
    const short* gB0 = W + (size_t)(n0 + rowS) * 512 + seg * 8;
    const short* gB1 = W + (size_t)(n0 + 64 + rowS) * 512 + seg * 8;
    short* lA0 = As + (size_t)tid * 8;
    short* lA1 = As + (size_t)(256 + tid) * 8;
    short* lB0 = Bs + (size_t)tid * 8;
    short* lB1 = Bs + (size_t)(256 + tid) * 8;

    for (int k0 = 0; k0 < 512; k0 += 32) {
        __syncthreads();
        async16(gA0 + k0, lA0);
        async16(gA1 + k0, lA1);
        async16(gB0 + k0, lB0);
        async16(gB1 + k0, lB1);
        __syncthreads();
        short8 a[4], b[4];
        #pragma unroll
        for (int mt = 0; mt < 4; ++mt)
            a[mt] = *(const short8*)(As + (msub + mt * 16 + col) * 32 + quad * 8);
        #pragma unroll
        for (int nt = 0; nt < 4; ++nt)
            b[nt] = *(const short8*)(Bs + (nsub + nt * 16 + col) * 32 + quad * 8);
        #pragma unroll
        for (int mt = 0; mt < 4; ++mt)
            #pragma unroll
            for (int nt = 0; nt < 4; ++nt)
                acc[mt][nt] = __builtin_amdgcn_mfma_f32_16x16x32_bf16(a[mt], b[nt], acc[mt][nt], 0, 0, 0);
    }

    #pragma unroll
    for (int nt = 0; nt < 4; ++nt) {
        float bv = bias[n0 + nsub + nt * 16 + col];
        #pragma unroll
        for (int mt = 0; mt < 4; ++mt) {
            #pragma unroll
            for (int r = 0; r < 4; ++r) {
                int m = m0 + msub + mt * 16 + quad * 4 + r;
                out[(size_t)m * 512 + n0 + nsub + nt * 16 + col] = f2bf(acc[mt][nt][r] + bv);
            }
        }
    }
}

// ---------------- fused attention ----------------
// grid: (qtile=8, h=8, b=32), block 256 (4 waves, 16 q-rows per wave)
__global__ __launch_bounds__(256) void attn_kernel(
    const short* __restrict__ Q, const short* __restrict__ K, const short* __restrict__ V,
    const float* __restrict__ qmask, const float* __restrict__ kmask,
    const int* __restrict__ caus, float* __restrict__ out, float* __restrict__ aw) {
    __shared__ short vt[64 * 72];        // V^T chunk: vt[d][kk], stride 72 (2-way bank alias = free)
    __shared__ short wl[4 * 16 * 72];    // per-wave w chunk (bf16, A-layout source)

    int tid = threadIdx.x;
    int lane = tid & 63, wv = tid >> 6;
    int col = lane & 15, quad = lane >> 4;
    int qt = blockIdx.x, h = blockIdx.y, b = blockIdx.z;
    int q0 = qt * 64 + wv * 16;          // this wave's q base (global within L)
    size_t rowbase = (size_t)b * 512;
    bool causal = (*caus) != 0;

    // Q A-frags (lane m=col holds k=quad*8+j, two 32-k chunks cover dh=64)
    short8 aQ0, aQ1;
    {
        const short* qp = Q + (rowbase + q0 + col) * 512 + h * 64 + quad * 8;
        aQ0 = *(const short8*)(qp);
        aQ1 = *(const short8*)(qp + 32);
    }

    // scores: 32 tiles of 16x16; lane holds rows quad*4+r, col = t*16 + (lane&15)
    float4v sc[32];
    const short* kp = K + (rowbase + col) * 512 + h * 64 + quad * 8;
    const float* kmp = kmask + b * 512;
    #pragma unroll
    for (int t = 0; t < 32; ++t) {
        short8 b0 = *(const short8*)(kp + (size_t)(t * 16) * 512);
        short8 b1 = *(const short8*)(kp + (size_t)(t * 16) * 512 + 32);
        float4v s; s[0]=0.f; s[1]=0.f; s[2]=0.f; s[3]=0.f;
        s = __builtin_amdgcn_mfma_f32_16x16x32_bf16(aQ0, b0, s, 0, 0, 0);
        s = __builtin_amdgcn_mfma_f32_16x16x32_bf16(aQ1, b1, s, 0, 0, 0);
        int kcol = t * 16 + col;
        float km = kmp[kcol];
        #pragma unroll
        for (int r = 0; r < 4; ++r) {
            float v = s[r] * 0.125f;  // 1/sqrt(64)
            int qg = q0 + quad * 4 + r;
            bool masked = (km == 0.f) || (causal && (kcol > qg));
            sc[t][r] = masked ? -INFINITY : v;
        }
    }

    // softmax over k (512 values per q-row: 32 per lane x 16 lanes in the quad-group)
    float mx[4], sm[4], inv[4];
    #pragma unroll
    for (int r = 0; r < 4; ++r) mx[r] = -INFINITY;
    #pragma unroll
    for (int t = 0; t < 32; ++t)
        #pragma unroll
        for (int r = 0; r < 4; ++r) mx[r] = fmaxf(mx[r], sc[t][r]);
    #pragma unroll
    for (int r = 0; r < 4; ++r) {
        #pragma unroll
        for (int off = 1; off < 16; off <<= 1) mx[r] = fmaxf(mx[r], __shfl_xor(mx[r], off, 64));
    }
    #pragma unroll
    for (int r = 0; r < 4; ++r) sm[r] = 0.f;
    #pragma unroll
    for (int t = 0; t < 32; ++t)
        #pragma unroll
        for (int r = 0; r < 4; ++r) {
            float s = sc[t][r];
            float e = (s == -INFINITY) ? 0.f : __expf(s - mx[r]);
            sc[t][r] = e;
            sm[r] += e;
        }
    #pragma unroll
    for (int r = 0; r < 4; ++r) {
        #pragma unroll
        for (int off = 1; off < 16; off <<= 1) sm[r] += __shfl_xor(sm[r], off, 64);
    }
    const float* qmp = qmask + b * 512;
    #pragma unroll
    for (int r = 0; r < 4; ++r) {
        float qm = qmp[q0 + quad * 4 + r];
        inv[r] = (sm[r] > 0.f) ? (qm / sm[r]) : 0.f;  // nan_to_num + post-softmax query mask
    }
    #pragma unroll
    for (int t = 0; t < 32; ++t)
        #pragma unroll
        for (int r = 0; r < 4; ++r) sc[t][r] *= inv[r];

    // write attention weights [B][H][Lq][Lk]
    float* awp = aw + ((size_t)b * 8 + h) * 512 * 512;
    #pragma unroll
    for (int t = 0; t < 32; ++t) {
        int kcol = t * 16 + col;
        #pragma unroll
        for (int r = 0; r < 4; ++r) {
            int qg = q0 + quad * 4 + r;
            awp[(size_t)qg * 512 + kcol] = sc[t][r];
        }
    }

    // PV: O[q][d] = sum_k w[q][k] * V[k][d], chunked over k in 8 chunks of 64
    float4v O[4];
    #pragma unroll
    for (int nt = 0; nt < 4; ++nt) { O[nt][0]=0.f; O[nt][1]=0.f; O[nt][2]=0.f; O[nt][3]=0.f; }
    short* wlw = wl + wv * (16 * 72);
    #pragma unroll
    for (int c = 0; c < 8; ++c) {
        __syncthreads();
        // stage V^T chunk: vt[d][kk] <- V[b*512 + c*64 + kk][h*64 + d]
        #pragma unroll
        for (int i = 0; i < 16; ++i) {
            int idx = i * 256 + tid;
            int kk = idx >> 6, d = idx & 63;
            vt[d * 72 + kk] = V[(rowbase + c * 64 + kk) * 512 + h * 64 + d];
        }
        // stage this wave's w chunk as bf16 in [q][kk] layout
        #pragma unroll
        for (int tl = 0; tl < 4; ++tl) {
            #pragma unroll
            for (int r = 0; r < 4; ++r)
                wlw[(quad * 4 + r) * 72 + tl * 16 + col] = f2bf(sc[c * 4 + tl][r]);
        }
        __syncthreads();
        #pragma unroll
        for (int sub = 0; sub < 2; ++sub) {
            short8 aW = *(const short8*)(wlw + col * 72 + sub * 32 + quad * 8);
            #pragma unroll
            for (int nt = 0; nt < 4; ++nt) {
                short8 bV = *(const short8*)(vt + (nt * 16 + col) * 72 + sub * 32 + quad * 8);
                O[nt] = __builtin_amdgcn_mfma_f32_16x16x32_bf16(aW, bV, O[nt], 0, 0, 0);
            }
        }
    }
    // out[b][l][h*64+d]
    #pragma unroll
    for (int nt = 0; nt < 4; ++nt) {
        #pragma unroll
        for (int r = 0; r < 4; ++r) {
            int qg = q0 + quad * 4 + r;
            out[(rowbase + qg) * 512 + h * 64 + nt * 16 + col] = O[nt][r];
        }
    }
}

extern "C" void kernel_launch(void* const* d_in, const int* in_sizes, int n_in,
                              void* d_out, int out_size, void* d_ws, size_t ws_size,
                              hipStream_t stream) {
    const float* queries = (const float*)d_in[0];
    const float* keys    = (const float*)d_in[1];
    const float* Wq      = (const float*)d_in[2];
    const float* bq      = (const float*)d_in[3];
    const float* Wk      = (const float*)d_in[4];
    const float* bk      = (const float*)d_in[5];
    const float* Wv      = (const float*)d_in[6];
    const float* bv      = (const float*)d_in[7];
    const int*   caus    = (const int*)d_in[8];

    const size_t NE = (size_t)16384 * 512;  // 8,388,608 elements per [B*L, D] tensor
    short* qbf = (short*)d_ws;
    short* kbf = qbf + NE;
    short* Qb  = kbf + NE;
    short* Kb  = Qb + NE;
    short* Vb  = Kb + NE;
    short* wqb = Vb + NE;
    short* wkb = wqb + 512 * 512;
    short* wvb = wkb + 512 * 512;
    float* qm  = (float*)(wvb + 512 * 512);
    float* km  = qm + 32 * 512;

    // fused fp32->bf16 + sign masks for queries/keys
    cvtmask_kernel<<<8192, 256, 0, stream>>>(queries, keys, qbf, kbf, qm, km);
    // weight converts
    cvt_kernel<<<256, 256, 0, stream>>>(Wq, wqb, 65536);
    cvt_kernel<<<256, 256, 0, stream>>>(Wk, wkb, 65536);
    cvt_kernel<<<256, 256, 0, stream>>>(Wv, wvb, 65536);
    // fused Q/K/V projection GEMMs
    dim3 pg(128, 4, 3);
    proj_kernel<<<pg, 256, 0, stream>>>(qbf, kbf, wqb, wkb, wvb, bq, bk, bv, Qb, Kb, Vb);
    // fused attention
    float* outp = (float*)d_out;
    float* awp  = outp + 8388608;
    dim3 ag(8, 8, 32);
    attn_kernel<<<ag, 256, 0, stream>>>(Qb, Kb, Vb, qm, km, caus, outp, awp);
}

// Round 3
// 513.534 us; speedup vs baseline: 1.4287x; 1.0520x over previous
//
#include <hip/hip_runtime.h>
#include <math.h>

typedef short short8 __attribute__((ext_vector_type(8)));
typedef short short4v __attribute__((ext_vector_type(4)));
typedef float float4v __attribute__((ext_vector_type(4)));

// bf16 round-to-nearest-even from fp32, as raw bits in a short
__device__ __forceinline__ short f2bf(float f) {
    union { float f; unsigned u; } v; v.f = f;
    unsigned r = (v.u + 0x7FFFu + ((v.u >> 16) & 1u)) >> 16;
    return (short)r;
}

__device__ __forceinline__ void async16(const short* g, short* l) {
    __builtin_amdgcn_global_load_lds(
        (const __attribute__((address_space(1))) unsigned*)g,
        (__attribute__((address_space(3))) unsigned*)l, 16, 0, 0);
}

// ---------------- fp32 -> bf16 convert (weights) ----------------
__global__ void cvt_kernel(const float* __restrict__ src, short* __restrict__ dst, int n4) {
    int i = blockIdx.x * blockDim.x + threadIdx.x;
    if (i < n4) {
        float4v v = ((const float4v*)src)[i];
        short4v o;
        o[0] = f2bf(v[0]); o[1] = f2bf(v[1]); o[2] = f2bf(v[2]); o[3] = f2bf(v[3]);
        ((short4v*)dst)[i] = o;
    }
}

// ---------------- fused fp32->bf16 + sign-mask for queries/keys ----------------
__global__ __launch_bounds__(256) void cvtmask_kernel(
    const float* __restrict__ q, const float* __restrict__ k,
    short* __restrict__ qb, short* __restrict__ kb,
    float* __restrict__ qm, float* __restrict__ km) {
    int tid = threadIdx.x;
    int lane = tid & 63, wv = tid >> 6;
    int row = blockIdx.x * 4 + wv;
    const float* src; short* dst; float* msk; int r;
    if (row < 16384) { src = q; dst = qb; msk = qm; r = row; }
    else             { src = k; dst = kb; msk = km; r = row - 16384; }
    const float4v* p = (const float4v*)(src + (size_t)r * 512);
    float4v a = p[lane];
    float4v b = p[lane + 64];
    short4v o1, o2;
    o1[0] = f2bf(a[0]); o1[1] = f2bf(a[1]); o1[2] = f2bf(a[2]); o1[3] = f2bf(a[3]);
    o2[0] = f2bf(b[0]); o2[1] = f2bf(b[1]); o2[2] = f2bf(b[2]); o2[3] = f2bf(b[3]);
    short4v* d4 = (short4v*)(dst + (size_t)r * 512);
    d4[lane] = o1;
    d4[lane + 64] = o2;
    float s = fabsf(a[0]) + fabsf(a[1]) + fabsf(a[2]) + fabsf(a[3])
            + fabsf(b[0]) + fabsf(b[1]) + fabsf(b[2]) + fabsf(b[3]);
    #pragma unroll
    for (int off = 1; off < 64; off <<= 1) s += __shfl_xor(s, off, 64);
    if (lane == 0) msk[r] = (s > 0.f) ? 1.f : 0.f;
}

// ---------------- fused projection GEMM (m97 structure, BK=64) ----------------
__global__ __launch_bounds__(256) void proj_kernel(
    const short* __restrict__ Xq, const short* __restrict__ Xk,
    const short* __restrict__ Wqp, const short* __restrict__ Wkp, const short* __restrict__ Wvp,
    const float* __restrict__ bqp, const float* __restrict__ bkp, const float* __restrict__ bvp,
    short* __restrict__ Qo, short* __restrict__ Ko, short* __restrict__ Vo) {
    __shared__ short As[128 * 64];
    __shared__ short Bs[128 * 64];
    int z = blockIdx.z;
    const short* X    = (z == 0) ? Xq  : Xk;
    const short* W    = (z == 0) ? Wqp : (z == 1) ? Wkp : Wvp;
    const float* bias = (z == 0) ? bqp : (z == 1) ? bkp : bvp;
    short* out        = (z == 0) ? Qo  : (z == 1) ? Ko  : Vo;

    int tid = threadIdx.x;
    int lane = tid & 63, wv = tid >> 6;
    int col = lane & 15, quad = lane >> 4;
    int m0 = blockIdx.x * 128;
    int n0 = blockIdx.y * 128;
    int msub = (wv & 1) * 64, nsub = (wv >> 1) * 64;

    float4v acc[4][4];
    #pragma unroll
    for (int mt = 0; mt < 4; ++mt)
        #pragma unroll
        for (int nt = 0; nt < 4; ++nt) { acc[mt][nt][0]=0.f; acc[mt][nt][1]=0.f; acc[mt][nt][2]=0.f; acc[mt][nt][3]=0.f; }

    int rowS = tid >> 3;   // 0..31
    int seg  = tid & 7;    // 16B segment within a 128B row
    const short* gA = X + (size_t)(m0 + rowS) * 512 + seg * 8;
    const short* gB = W + (size_t)(n0 + rowS) * 512 + seg * 8;
    short* lA = As + (size_t)tid * 8;
    short* lB = Bs + (size_t)tid * 8;

    for (int k0 = 0; k0 < 512; k0 += 64) {
        __syncthreads();
        #pragma unroll
        for (int j = 0; j < 4; ++j) {
            async16(gA + (size_t)(j * 32) * 512 + k0, lA + j * 2048);
            async16(gB + (size_t)(j * 32) * 512 + k0, lB + j * 2048);
        }
        __syncthreads();
        #pragma unroll
        for (int ksub = 0; ksub < 2; ++ksub) {
            short8 a[4], b[4];
            #pragma unroll
            for (int mt = 0; mt < 4; ++mt)
                a[mt] = *(const short8*)(As + (msub + mt * 16 + col) * 64 + ksub * 32 + quad * 8);
            #pragma unroll
            for (int nt = 0; nt < 4; ++nt)
                b[nt] = *(const short8*)(Bs + (nsub + nt * 16 + col) * 64 + ksub * 32 + quad * 8);
            #pragma unroll
            for (int mt = 0; mt < 4; ++mt)
                #pragma unroll
                for (int nt = 0; nt < 4; ++nt)
                    acc[mt][nt] = __builtin_amdgcn_mfma_f32_16x16x32_bf16(a[mt], b[nt], acc[mt][nt], 0, 0, 0);
        }
    }

    #pragma unroll
    for (int nt = 0; nt < 4; ++nt) {
        float bv = bias[n0 + nsub + nt * 16 + col];
        #pragma unroll
        for (int mt = 0; mt < 4; ++mt) {
            #pragma unroll
            for (int r = 0; r < 4; ++r) {
                int m = m0 + msub + mt * 16 + quad * 4 + r;
                out[(size_t)m * 512 + n0 + nsub + nt * 16 + col] = f2bf(acc[mt][nt][r] + bv);
            }
        }
    }
}

// ---------------- fused attention ----------------
// grid: (bh=256, qt=8) so all 8 q-tiles of one (b,h) land on one XCD (linear%8)
// block 256 = 4 waves, 16 q-rows per wave. Scores computed TRANSPOSED:
// D[kk][q] via mfma(A=K-rows, B=Q-rows): lane holds q=col, kk = t*16+quad*4+r
// -> aw store is dwordx4 per lane, softmax reduce is 2 shuffles (xor 16,32).
__global__ __launch_bounds__(256) void attn_kernel(
    const short* __restrict__ Q, const short* __restrict__ K, const short* __restrict__ V,
    const float* __restrict__ qmask, const float* __restrict__ kmask,
    const int* __restrict__ caus, float* __restrict__ out, float* __restrict__ aw) {
    __shared__ short vt[64 * 72];        // V^T chunk: vt[d][kk], stride 72
    __shared__ short wl[4 * 16 * 72];    // per-wave w chunk [q][kk], stride 72

    int tid = threadIdx.x;
    int lane = tid & 63, wv = tid >> 6;
    int col = lane & 15, quad = lane >> 4;
    int bh = blockIdx.x, qt = blockIdx.y;
    int b = bh >> 3, h = bh & 7;
    int q0 = qt * 64 + wv * 16;
    size_t rowbase = (size_t)b * 512;
    bool causal = (*caus) != 0;

    // Q B-frags: lane n=col -> q-row q0+col, k = quad*8+j (two 32-chunks over dh=64)
    short8 bQ0, bQ1;
    {
        const short* qp = Q + (rowbase + q0 + col) * 512 + h * 64 + quad * 8;
        bQ0 = *(const short8*)(qp);
        bQ1 = *(const short8*)(qp + 32);
    }

    // scores (transposed): sc[t][r] = S[kk = t*16+quad*4+r][q = q0+col]
    float4v sc[32];
    const short* kp = K + (rowbase + col) * 512 + h * 64 + quad * 8;
    const float* kmp = kmask + b * 512;
    int qg = q0 + col;
    #pragma unroll
    for (int t = 0; t < 32; ++t) {
        short8 aK0 = *(const short8*)(kp + (size_t)(t * 16) * 512);
        short8 aK1 = *(const short8*)(kp + (size_t)(t * 16) * 512 + 32);
        float4v s; s[0]=0.f; s[1]=0.f; s[2]=0.f; s[3]=0.f;
        s = __builtin_amdgcn_mfma_f32_16x16x32_bf16(aK0, bQ0, s, 0, 0, 0);
        s = __builtin_amdgcn_mfma_f32_16x16x32_bf16(aK1, bQ1, s, 0, 0, 0);
        int kb = t * 16 + quad * 4;
        float4v km4 = *(const float4v*)(kmp + kb);
        #pragma unroll
        for (int r = 0; r < 4; ++r) {
            float v = s[r] * 0.125f;  // 1/sqrt(64)
            bool masked = (km4[r] == 0.f) || (causal && (kb + r > qg));
            sc[t][r] = masked ? -INFINITY : v;
        }
    }

    // softmax over k: per lane all 128 values share q=col; reduce across quads
    float mx = -INFINITY;
    #pragma unroll
    for (int t = 0; t < 32; ++t)
        #pragma unroll
        for (int r = 0; r < 4; ++r) mx = fmaxf(mx, sc[t][r]);
    mx = fmaxf(mx, __shfl_xor(mx, 16, 64));
    mx = fmaxf(mx, __shfl_xor(mx, 32, 64));
    float sm = 0.f;
    #pragma unroll
    for (int t = 0; t < 32; ++t)
        #pragma unroll
        for (int r = 0; r < 4; ++r) {
            float s = sc[t][r];
            float e = (s == -INFINITY) ? 0.f : __expf(s - mx);
            sc[t][r] = e;
            sm += e;
        }
    sm += __shfl_xor(sm, 16, 64);
    sm += __shfl_xor(sm, 32, 64);
    float qmv = qmask[b * 512 + qg];
    float inv = (sm > 0.f) ? (qmv / sm) : 0.f;  // nan_to_num + post-softmax query mask
    #pragma unroll
    for (int t = 0; t < 32; ++t)
        #pragma unroll
        for (int r = 0; r < 4; ++r) sc[t][r] *= inv;

    // attention weights [B][H][Lq][Lk]: lane holds 4 consecutive k -> dwordx4
    {
        float* awr = aw + ((size_t)b * 8 + h) * 512 * 512 + (size_t)qg * 512 + quad * 4;
        #pragma unroll
        for (int t = 0; t < 32; ++t)
            *(float4v*)(awr + t * 16) = sc[t];
    }

    // PV: O[q][d] = sum_k w[q][k] * V[k][d], chunks of 64 k
    float4v O[4];
    #pragma unroll
    for (int nt = 0; nt < 4; ++nt) { O[nt][0]=0.f; O[nt][1]=0.f; O[nt][2]=0.f; O[nt][3]=0.f; }
    short* wlw = wl + wv * (16 * 72);
    #pragma unroll
    for (int c = 0; c < 8; ++c) {
        __syncthreads();
        // stage V^T chunk: vt[d][kk] <- V[b*512 + c*64 + kk][h*64 + d], vectorized loads
        #pragma unroll
        for (int i = 0; i < 2; ++i) {
            int idx = i * 256 + tid;
            int kk = idx >> 3, sg = idx & 7;
            short8 v8 = *(const short8*)(V + (rowbase + c * 64 + kk) * 512 + h * 64 + sg * 8);
            #pragma unroll
            for (int j = 0; j < 8; ++j)
                vt[(sg * 8 + j) * 72 + kk] = v8[j];
        }
        // stage this wave's w chunk as bf16 [q][kk]: lane writes 4 consecutive kk
        #pragma unroll
        for (int tl = 0; tl < 4; ++tl) {
            int t = c * 4 + tl;
            short4v w4;
            #pragma unroll
            for (int r = 0; r < 4; ++r) w4[r] = f2bf(sc[t][r]);
            *(short4v*)(wlw + col * 72 + tl * 16 + quad * 4) = w4;
        }
        __syncthreads();
        #pragma unroll
        for (int sub = 0; sub < 2; ++sub) {
            short8 aW = *(const short8*)(wlw + col * 72 + sub * 32 + quad * 8);
            #pragma unroll
            for (int nt = 0; nt < 4; ++nt) {
                short8 bV = *(const short8*)(vt + (nt * 16 + col) * 72 + sub * 32 + quad * 8);
                O[nt] = __builtin_amdgcn_mfma_f32_16x16x32_bf16(aW, bV, O[nt], 0, 0, 0);
            }
        }
    }
    // out[b][l][h*64+d]; D[q][d]: row=quad*4+r is q-offset, col is d
    #pragma unroll
    for (int nt = 0; nt < 4; ++nt) {
        #pragma unroll
        for (int r = 0; r < 4; ++r) {
            int qq = q0 + quad * 4 + r;
            out[(rowbase + qq) * 512 + h * 64 + nt * 16 + col] = O[nt][r];
        }
    }
}

extern "C" void kernel_launch(void* const* d_in, const int* in_sizes, int n_in,
                              void* d_out, int out_size, void* d_ws, size_t ws_size,
                              hipStream_t stream) {
    const float* queries = (const float*)d_in[0];
    const float* keys    = (const float*)d_in[1];
    const float* Wq      = (const float*)d_in[2];
    const float* bq      = (const float*)d_in[3];
    const float* Wk      = (const float*)d_in[4];
    const float* bk      = (const float*)d_in[5];
    const float* Wv      = (const float*)d_in[6];
    const float* bv      = (const float*)d_in[7];
    const int*   caus    = (const int*)d_in[8];

    const size_t NE = (size_t)16384 * 512;
    short* qbf = (short*)d_ws;
    short* kbf = qbf + NE;
    short* Qb  = kbf + NE;
    short* Kb  = Qb + NE;
    short* Vb  = Kb + NE;
    short* wqb = Vb + NE;
    short* wkb = wqb + 512 * 512;
    short* wvb = wkb + 512 * 512;
    float* qm  = (float*)(wvb + 512 * 512);
    float* km  = qm + 32 * 512;

    cvtmask_kernel<<<8192, 256, 0, stream>>>(queries, keys, qbf, kbf, qm, km);
    cvt_kernel<<<256, 256, 0, stream>>>(Wq, wqb, 65536);
    cvt_kernel<<<256, 256, 0, stream>>>(Wk, wkb, 65536);
    cvt_kernel<<<256, 256, 0, stream>>>(Wv, wvb, 65536);
    dim3 pg(128, 4, 3);
    proj_kernel<<<pg, 256, 0, stream>>>(qbf, kbf, wqb, wkb, wvb, bq, bk, bv, Qb, Kb, Vb);
    float* outp = (float*)d_out;
    float* awp  = outp + 8388608;
    dim3 ag(256, 8);
    attn_kernel<<<ag, 256, 0, stream>>>(Qb, Kb, Vb, qm, km, caus, outp, awp);
}